// Round 10
// baseline (358.645 us; speedup 1.0000x reference)
//
#include <hip/hip_runtime.h>
#include <cstdint>
#include <cstddef>

#define Bb 128
#define Tt 2048
#define Dd 512
#define Hh 512
#define Mtot (Bb*Tt)
#define NG 1152   // scores grid; grid-stride covers pathological masks

typedef __attribute__((ext_vector_type(8))) _Float16 h8;
typedef __attribute__((ext_vector_type(4))) _Float16 h4v;
typedef __attribute__((ext_vector_type(4))) float f4;

// Direct global->LDS DMA, 16B per lane. LDS dest is WAVE-UNIFORM base; HW
// writes lane l at base + l*16. Global src is per-lane (pre-swizzled).
#define GLOAD_LDS16(gsrc, ldst) \
    __builtin_amdgcn_global_load_lds((const __attribute__((address_space(1))) void*)(gsrc), \
                                     (__attribute__((address_space(3))) void*)(ldst), 16, 0, 0)

__device__ __forceinline__ h4v cvt4s(const float4 a) {
    h4v h;
    h[0] = (_Float16)a.x; h[1] = (_Float16)a.y;
    h[2] = (_Float16)a.z; h[3] = (_Float16)a.w;
    return h;
}

// ---------------- kernel 1: fused prep ----------------
// blocks [0,1024)   : W -> fp16 cast
// blocks [1024,1152): per-b mask compaction + scores zeroing + tile work-list
// blocks [1152,1408): col_t = relu(col @ W^T) fp32 (2 blocks per b)
__global__ __launch_bounds__(256) void prep_kernel(
    const float* __restrict__ W, _Float16* __restrict__ W16,
    const int* __restrict__ mask, int* __restrict__ cidx, int* __restrict__ cnt,
    float* __restrict__ scores, int* __restrict__ tlist, int* __restrict__ ntiles,
    const float* __restrict__ col, float* __restrict__ colt)
{
    const int blk = blockIdx.x, tid = threadIdx.x;
    if (blk < 1024) {                       // ---- W16 cast ----
        int i = blk * 256 + tid;
        W16[i] = (_Float16)W[i];
        return;
    }
    if (blk < 1152) {                       // ---- compaction (b = blk-1024) ----
        __shared__ int wsum[4];
        int b = blk - 1024;
        const int* mrow = mask + (size_t)b * Tt;
        float* srow = scores + (size_t)b * Tt;
        int mv[8], c = 0;
#pragma unroll
        for (int i = 0; i < 8; i++) {
            mv[i] = mrow[tid * 8 + i];
            c += mv[i];
            srow[tid * 8 + i] = 0.f;        // masked entries stay 0
        }
        int lane = tid & 63, wv = tid >> 6;
        int inc = c;
#pragma unroll
        for (int off = 1; off < 64; off <<= 1) {
            int n = __shfl_up(inc, off);
            if (lane >= off) inc += n;
        }
        if (lane == 63) wsum[wv] = inc;
        __syncthreads();
        int wbase = 0;
        for (int w = 0; w < wv; w++) wbase += wsum[w];
        int pos = wbase + inc - c;          // exclusive prefix
        int* crow = cidx + (size_t)b * Tt;
#pragma unroll
        for (int i = 0; i < 8; i++)
            if (mv[i]) crow[pos++] = tid * 8 + i;
        if (tid == 255) {
            int total = wbase + inc;
            cnt[b] = total;
            int nt = (total + 127) >> 7;    // tiles of 128 rows
            int base = atomicAdd(ntiles, nt);
            for (int i = 0; i < nt; i++) tlist[base + i] = (b << 8) | i;
        }
        return;
    }
    {                                        // ---- col_proj ----
        __shared__ float c[Dd];
        int idx = blk - 1152;
        int b = idx >> 1;
        int h = (idx & 1) * 256 + tid;
        c[tid] = col[b * Dd + tid];
        c[tid + 256] = col[b * Dd + 256 + tid];
        __syncthreads();
        const f4* w4 = (const f4*)(W + (size_t)h * Dd);
        float acc = 0.f;
#pragma unroll 8
        for (int k = 0; k < Dd / 4; k++) {
            f4 w = w4[k];
            acc += w.x * c[4 * k] + w.y * c[4 * k + 1] + w.z * c[4 * k + 2] + w.w * c[4 * k + 3];
        }
        colt[b * Hh + h] = fmaxf(acc, 0.f);
    }
}

// ---------------- kernel 2: pipelined scores GEMM, BM=128, 1024 threads -------
// UNCHANGED from R9. Launched TWICE this round (idempotent: pure function of
// inputs, unique writer per output element) to measure its exact duration as
// total_R10 - total_R9. See round journal: this is a deliberate measurement.
__global__ __launch_bounds__(1024, 4) void scores_kernel(
    const float* __restrict__ X,        // [B*T][512]
    const _Float16* __restrict__ W16,   // [512][512]
    const float* __restrict__ colt,     // [128][512]
    const int* __restrict__ cidx,       // [B][T]
    const int* __restrict__ cnt,        // [B]
    const int* __restrict__ tlist,      // work list: (b<<8)|tile
    const int* __restrict__ ntiles,     // [1]
    float* __restrict__ scores)         // [B*T], pre-zeroed
{
    const int tid = threadIdx.x;
    const int total = ntiles[0];

    __shared__ __align__(16) char lds[81920];
    float (*sred)[128] = (float(*)[128])(lds + 65536);

    const int wave = tid >> 6;
    const int lane = tid & 63;
    const int wm = wave >> 2;   // 0..3 : M quarter (rows wm*32..+32)
    const int wn = wave & 3;    // 0..3 : N strip (cols wn*128..+128)
    const int l16 = lane & 15;
    const int khi = lane >> 4;  // 0..3

    int wsrcoff[2];
#pragma unroll
    for (int j = 0; j < 2; j++) {
        int r = (j * 16 + wave) * 16 + (lane >> 2);
        int c = (lane & 3) ^ ((r >> 1) & 3);
        wsrcoff[j] = r * Dd + c * 8;
    }
    const int wldsoff = wave * 1024;   // + j*16384 per chunk-call

    const int xrow = tid >> 3, xf4 = tid & 7;
    const int xoff = xrow * 64 + (((xf4 >> 1) ^ ((xrow >> 1) & 3)) << 4) + (xf4 & 1) * 8;

    for (int idx = blockIdx.x; idx < total; idx += NG) {
        const int ent = tlist[idx];
        const int b = ent >> 8;
        const int tile = ent & 255;
        const int count = cnt[b];
        const int r0 = tile * 128;

        const int* crow = cidx + (size_t)b * Tt;
        int rl = r0 + xrow; if (rl >= count) rl = count - 1;  // clamp (dup, never stored)
        const float* xsrc = X + ((size_t)b * Tt + crow[rl]) * Dd + xf4 * 4;

        f4 acc[2][8];
#pragma unroll
        for (int i = 0; i < 2; i++)
#pragma unroll
            for (int j = 0; j < 8; j++) {
                f4 z = {0.f, 0.f, 0.f, 0.f};
                acc[i][j] = z;
            }

        // ---- prologue: W_0 DMA -> bufW0; X_0 -> LDS; X_1 -> regs ----
        __builtin_amdgcn_sched_barrier(0);
#pragma unroll
        for (int j = 0; j < 2; j++)
            GLOAD_LDS16(W16 + wsrcoff[j], lds + wldsoff + j * 16384);
        __builtin_amdgcn_sched_barrier(0);
        float4 x0 = *(const float4*)(xsrc);
        float4 xu = *(const float4*)(xsrc + 32);
        __builtin_amdgcn_sched_barrier(0);
        *(h4v*)(lds + 65536 + xoff) = cvt4s(x0);   // wait for x0 drains W_0 too (in-order)
        asm volatile("s_waitcnt vmcnt(1) lgkmcnt(0)" ::: "memory");
        __builtin_amdgcn_sched_barrier(0);
        __builtin_amdgcn_s_barrier();
        __builtin_amdgcn_sched_barrier(0);

#pragma unroll 2
        for (int t = 0; t < 16; ++t) {
            const int cur = t & 1;
            const int kW = (t < 15 ? t + 1 : 15) * 32;  // halfs (tail: dead re-stage)
            const int kX = (t < 14 ? t + 2 : 15) * 32;  // floats (tail: dead load)

            // ---- issue W_{t+1} DMA into bufW[cur^1], then X_{t+2} load ----
            char* bufWn = lds + (cur ^ 1) * 32768;
            __builtin_amdgcn_sched_barrier(0);
#pragma unroll
            for (int j = 0; j < 2; j++)
                GLOAD_LDS16(W16 + wsrcoff[j] + kW, bufWn + wldsoff + j * 16384);
            __builtin_amdgcn_sched_barrier(0);
            float4 xn = *(const float4*)(xsrc + kX);
            __builtin_amdgcn_sched_barrier(0);

            // ---- compute tile t from buf[cur] ----
            const char* bW = lds + cur * 32768;
            const char* bX = lds + 65536 + cur * 8192;
            h8 a[2];
#pragma unroll
            for (int mr = 0; mr < 2; mr++) {
                int row = wm * 32 + mr * 16 + l16;
                a[mr] = *(const h8*)(bX + row * 64 + ((khi ^ ((row >> 1) & 3)) << 4));
            }
#pragma unroll
            for (int nr = 0; nr < 8; nr++) {
                int row = wn * 128 + nr * 16 + l16;
                h8 bf = *(const h8*)(bW + row * 64 + ((khi ^ ((row >> 1) & 3)) << 4));
                acc[0][nr] = __builtin_amdgcn_mfma_f32_16x16x32_f16(a[0], bf, acc[0][nr], 0, 0, 0);
                acc[1][nr] = __builtin_amdgcn_mfma_f32_16x16x32_f16(a[1], bf, acc[1][nr], 0, 0, 0);
            }

            // ---- write X_{t+1} (regs xu) into bufX[cur^1] ----
            *(h4v*)(lds + 65536 + (cur ^ 1) * 8192 + xoff) = cvt4s(xu);
            // Queue = {W1,W2,X}: vmcnt(1) certifies the W-DMAs, keeps the X
            // prefetch in flight; lgkmcnt(0) publishes ds_writes.
            asm volatile("s_waitcnt vmcnt(1) lgkmcnt(0)" ::: "memory");
            __builtin_amdgcn_sched_barrier(0);
            __builtin_amdgcn_s_barrier();
            __builtin_amdgcn_sched_barrier(0);
            xu = xn;
        }

        // ---- epilogue: relu * colt, reduce over N ----
        float rs[2][4];
#pragma unroll
        for (int mr = 0; mr < 2; mr++)
#pragma unroll
            for (int r = 0; r < 4; r++) rs[mr][r] = 0.f;
#pragma unroll
        for (int nr = 0; nr < 8; nr++) {
            float cv = colt[b * Hh + wn * 128 + nr * 16 + l16];
#pragma unroll
            for (int mr = 0; mr < 2; mr++)
#pragma unroll
                for (int r = 0; r < 4; r++)
                    rs[mr][r] += fmaxf(acc[mr][nr][r], 0.f) * cv;
        }
#pragma unroll
        for (int mr = 0; mr < 2; mr++)
#pragma unroll
            for (int r = 0; r < 4; r++) {
                float v = rs[mr][r];
                v += __shfl_xor(v, 1);
                v += __shfl_xor(v, 2);
                v += __shfl_xor(v, 4);
                v += __shfl_xor(v, 8);
                rs[mr][r] = v;
            }
        if (l16 == 0) {
#pragma unroll
            for (int mr = 0; mr < 2; mr++)
#pragma unroll
                for (int r = 0; r < 4; r++)
                    sred[wn][wm * 32 + mr * 16 + khi * 4 + r] = rs[mr][r];
        }
        __syncthreads();
        if (tid < 128) {
            int r = r0 + tid;
            if (r < count) {
                float s = sred[0][tid] + sred[1][tid] + sred[2][tid] + sred[3][tid];
                scores[(size_t)b * Tt + crow[r]] = s;  // mask==1 here
            }
        }
        __syncthreads();   // protect sred/bufX before next work-list iteration
    }
}

// ---------------- kernel 3: softmax per b (IN-PLACE) + copy col into cat ------
__global__ void softmax_kernel(const float* __restrict__ scores, const float* __restrict__ col,
                               float* __restrict__ attn, float* __restrict__ out) {
    __shared__ float sm[256];
    int b = blockIdx.x, tid = threadIdx.x;
    const float* srow = scores + (size_t)b * Tt;
    float v[8];
#pragma unroll
    for (int i = 0; i < 8; i++) v[i] = srow[tid + i * 256];
    float mx = -1e30f;
#pragma unroll
    for (int i = 0; i < 8; i++) mx = fmaxf(mx, v[i]);
    sm[tid] = mx;
    __syncthreads();
    for (int s = 128; s > 0; s >>= 1) {
        if (tid < s) sm[tid] = fmaxf(sm[tid], sm[tid + s]);
        __syncthreads();
    }
    float M = sm[0];
    __syncthreads();
    float e[8];
    float sum = 0.f;
#pragma unroll
    for (int i = 0; i < 8; i++) {
        e[i] = __expf(v[i] - M);
        sum += e[i];
    }
    sm[tid] = sum;
    __syncthreads();
    for (int s = 128; s > 0; s >>= 1) {
        if (tid < s) sm[tid] += sm[tid + s];
        __syncthreads();
    }
    float inv = 1.f / sm[0];
    float* arow = attn + (size_t)b * Tt;
#pragma unroll
    for (int i = 0; i < 8; i++) arow[tid + i * 256] = e[i] * inv;
    for (int d = tid; d < Dd; d += 256) out[(size_t)b * 1024 + d] = col[(size_t)b * Dd + d];
}

// ---------------- kernel 4: weighted sums over COMPACTED t ----------------
__global__ void wsum_kernel(const float* __restrict__ attn, const float* __restrict__ X,
                            const int* __restrict__ cidx, const int* __restrict__ cnt,
                            float* __restrict__ part) {
    int dh = blockIdx.x;   // 0..1
    int tc = blockIdx.y;   // 0..3
    int b  = blockIdx.z;   // 0..127
    int tid = threadIdx.x; // 256
    int d = dh * 256 + tid;
    int count = cnt[b];
    int base = tc * 512;
    int lim = count - base; if (lim > 512) lim = 512; if (lim < 0) lim = 0;
    __shared__ float sa[512];
    __shared__ int  sidx[512];
    const int* crow = cidx + (size_t)b * Tt;
    for (int j = tid; j < 512; j += 256) {
        int r = base + j;
        bool v = r < count;
        int t = v ? crow[r] : 0;
        sidx[j] = t;
        sa[j] = v ? attn[(size_t)b * Tt + t] : 0.f;
    }
    __syncthreads();
    float acc = 0.f;
    const float* xb = X + (size_t)b * Tt * Dd + d;
#pragma unroll 4
    for (int j = 0; j < lim; j++) acc += sa[j] * xb[(size_t)sidx[j] * Dd];
    part[((size_t)b * 4 + tc) * Dd + d] = acc;
}

// ---------------- kernel 5: combine partials, write both outputs ----------------
__global__ void combine_kernel(const float* __restrict__ part, float* __restrict__ out) {
    int i = blockIdx.x * 256 + threadIdx.x;  // < 65536
    int b = i >> 9, d = i & 511;
    float s = 0.f;
#pragma unroll
    for (int tc = 0; tc < 4; tc++) s += part[((size_t)b * 4 + tc) * Dd + d];
    out[(size_t)b * 1024 + 512 + d] = s;                 // cat section, second half
    out[(size_t)Bb * 1024 + (size_t)b * 512 + d] = s;    // attention_output section
}

extern "C" void kernel_launch(void* const* d_in, const int* in_sizes, int n_in,
                              void* d_out, int out_size, void* d_ws, size_t ws_size,
                              hipStream_t stream) {
    const float* col  = (const float*)d_in[0];   // [128,512]
    const float* X    = (const float*)d_in[1];   // [128,2048,512]
    const int*   mask = (const int*)d_in[2];     // [128,2048]
    const float* W    = (const float*)d_in[3];   // [512,512]
    float* out = (float*)d_out;

    char* ws = (char*)d_ws;
    _Float16* W16   = (_Float16*)ws;                     // 0    .. 512K
    float*    colt  = (float*)(ws + (512 << 10));        // 512K .. 768K
    float*    scores= (float*)(ws + (768 << 10));        // 768K .. 1792K
    float*    attn  = scores;                            // softmax in-place
    float*    part  = (float*)(ws + (1792 << 10));       // 1792K.. 2816K
    int*      cidx  = (int*)(ws + (2816 << 10));         // 2816K.. 3840K
    int*      cnt   = (int*)(ws + (3840 << 10));         // 3840K.. +512B
    int*      tlist = (int*)(ws + (3841 << 10));         // 3841K.. +16KB
    int*      ntile = (int*)(ws + (3860 << 10));         // 3860K.. +4B

    hipMemsetAsync(ntile, 0, 4, stream);
    hipLaunchKernelGGL(prep_kernel, dim3(1408), dim3(256), 0, stream,
                       W, W16, mask, cidx, cnt, scores, tlist, ntile, col, colt);
    // MEASUREMENT: scores launched twice (idempotent). scores_dur =
    // total_R10 - total_R9 - launch overhead. Remove the duplicate next round.
    hipLaunchKernelGGL(scores_kernel, dim3(NG), dim3(1024), 0, stream,
                       X, W16, colt, cidx, cnt, tlist, ntile, scores);
    hipLaunchKernelGGL(scores_kernel, dim3(NG), dim3(1024), 0, stream,
                       X, W16, colt, cidx, cnt, tlist, ntile, scores);
    hipLaunchKernelGGL(softmax_kernel, dim3(Bb), dim3(256), 0, stream, scores, col, attn, out);
    hipLaunchKernelGGL(wsum_kernel, dim3(2, 4, Bb), dim3(256), 0, stream, attn, X, cidx, cnt, part);
    hipLaunchKernelGGL(combine_kernel, dim3(65536 / 256), dim3(256), 0, stream, part, out);
}

// Round 11
// 274.775 us; speedup vs baseline: 1.3052x; 1.3052x over previous
//
#include <hip/hip_runtime.h>
#include <cstdint>
#include <cstddef>

#define Bb 128
#define Tt 2048
#define Dd 512
#define Hh 512
#define Mtot (Bb*Tt)
#define NG 1152   // scores grid; grid-stride covers pathological masks

typedef __attribute__((ext_vector_type(8))) _Float16 h8;
typedef __attribute__((ext_vector_type(4))) _Float16 h4v;
typedef __attribute__((ext_vector_type(4))) float f4;

// Direct global->LDS DMA, 16B per lane. LDS dest is WAVE-UNIFORM base; HW
// writes lane l at base + l*16. Global src is per-lane (pre-swizzled).
#define GLOAD_LDS16(gsrc, ldst) \
    __builtin_amdgcn_global_load_lds((const __attribute__((address_space(1))) void*)(gsrc), \
                                     (__attribute__((address_space(3))) void*)(ldst), 16, 0, 0)

__device__ __forceinline__ h4v cvt4s(const float4 a) {
    h4v h;
    h[0] = (_Float16)a.x; h[1] = (_Float16)a.y;
    h[2] = (_Float16)a.z; h[3] = (_Float16)a.w;
    return h;
}

// ---------------- kernel 1: fused prep ----------------
// blocks [0,1024)   : W -> fp16 cast
// blocks [1024,1152): per-b mask compaction + tile work-list
// blocks [1152,1408): col_t = relu(col @ W^T) fp32 (2 blocks per b)
__global__ __launch_bounds__(256) void prep_kernel(
    const float* __restrict__ W, _Float16* __restrict__ W16,
    const int* __restrict__ mask, int* __restrict__ cidx, int* __restrict__ cnt,
    int* __restrict__ tlist, int* __restrict__ ntiles,
    const float* __restrict__ col, float* __restrict__ colt)
{
    const int blk = blockIdx.x, tid = threadIdx.x;
    if (blk < 1024) {                       // ---- W16 cast ----
        int i = blk * 256 + tid;
        W16[i] = (_Float16)W[i];
        return;
    }
    if (blk < 1152) {                       // ---- compaction (b = blk-1024) ----
        __shared__ int wsum[4];
        int b = blk - 1024;
        const int* mrow = mask + (size_t)b * Tt;
        int mv[8], c = 0;
#pragma unroll
        for (int i = 0; i < 8; i++) {
            mv[i] = mrow[tid * 8 + i];
            c += mv[i];
        }
        int lane = tid & 63, wv = tid >> 6;
        int inc = c;
#pragma unroll
        for (int off = 1; off < 64; off <<= 1) {
            int n = __shfl_up(inc, off);
            if (lane >= off) inc += n;
        }
        if (lane == 63) wsum[wv] = inc;
        __syncthreads();
        int wbase = 0;
        for (int w = 0; w < wv; w++) wbase += wsum[w];
        int pos = wbase + inc - c;          // exclusive prefix
        int* crow = cidx + (size_t)b * Tt;
#pragma unroll
        for (int i = 0; i < 8; i++)
            if (mv[i]) crow[pos++] = tid * 8 + i;
        if (tid == 255) {
            int total = wbase + inc;
            cnt[b] = total;
            int nt = (total + 127) >> 7;    // tiles of 128 rows
            int base = atomicAdd(ntiles, nt);
            for (int i = 0; i < nt; i++) tlist[base + i] = (b << 8) | i;
        }
        return;
    }
    {                                        // ---- col_proj ----
        __shared__ float c[Dd];
        int idx = blk - 1152;
        int b = idx >> 1;
        int h = (idx & 1) * 256 + tid;
        c[tid] = col[b * Dd + tid];
        c[tid + 256] = col[b * Dd + 256 + tid];
        __syncthreads();
        const f4* w4 = (const f4*)(W + (size_t)h * Dd);
        float acc = 0.f;
#pragma unroll 8
        for (int k = 0; k < Dd / 4; k++) {
            f4 w = w4[k];
            acc += w.x * c[4 * k] + w.y * c[4 * k + 1] + w.z * c[4 * k + 2] + w.w * c[4 * k + 3];
        }
        colt[b * Hh + h] = fmaxf(acc, 0.f);
    }
}

// ---------------- kernel 2: pipelined scores GEMM + compacted fp16 X emit -----
// BM=128, BN=512, BK=32, 16 K-steps, 16 waves = 4M x 4N, wave tile 32x128.
// NEW vs R9: the X stager also stores its fp16 h4v to Xc (dense compacted
// copy) -- wsum then reads 134MB fp16 dense instead of 268MB gathered fp32.
// vmcnt recount with the store in the queue (FIFO, issue order):
// entering step t: [Xload(t+1), ST(t-1)]... at pre-barrier wait the queue is
// [ST(t-1), W1, W2, Xload(t+2), ST(t)] -> vmcnt(2) retires ST(t-1),W1,W2
// (the DMAs the barrier must certify) and leaves {Xload, ST} in flight.
__global__ __launch_bounds__(1024, 4) void scores_kernel(
    const float* __restrict__ X,        // [B*T][512]
    const _Float16* __restrict__ W16,   // [512][512]
    const float* __restrict__ colt,     // [128][512]
    const int* __restrict__ cidx,       // [B][T]
    const int* __restrict__ cnt,        // [B]
    const int* __restrict__ tlist,      // work list: (b<<8)|tile
    const int* __restrict__ ntiles,     // [1]
    float* __restrict__ scores,         // [B*T] (masked entries untouched)
    _Float16* __restrict__ Xc)          // [B*T][512] compacted fp16 rows
{
    const int tid = threadIdx.x;
    const int total = ntiles[0];

    __shared__ __align__(16) char lds[81920];
    float (*sred)[128] = (float(*)[128])(lds + 65536);

    const int wave = tid >> 6;
    const int lane = tid & 63;
    const int wm = wave >> 2;   // 0..3 : M quarter (rows wm*32..+32)
    const int wn = wave & 3;    // 0..3 : N strip (cols wn*128..+128)
    const int l16 = lane & 15;
    const int khi = lane >> 4;  // 0..3

    int wsrcoff[2];
#pragma unroll
    for (int j = 0; j < 2; j++) {
        int r = (j * 16 + wave) * 16 + (lane >> 2);
        int c = (lane & 3) ^ ((r >> 1) & 3);
        wsrcoff[j] = r * Dd + c * 8;
    }
    const int wldsoff = wave * 1024;   // + j*16384 per chunk-call

    const int xrow = tid >> 3, xf4 = tid & 7;
    const int xoff = xrow * 64 + (((xf4 >> 1) ^ ((xrow >> 1) & 3)) << 4) + (xf4 & 1) * 8;

    for (int idx = blockIdx.x; idx < total; idx += NG) {
        const int ent = tlist[idx];
        const int b = ent >> 8;
        const int tile = ent & 255;
        const int count = cnt[b];
        const int r0 = tile * 128;

        const int* crow = cidx + (size_t)b * Tt;
        int rl = r0 + xrow; if (rl >= count) rl = count - 1;  // clamp (dup, never stored)
        const float* xsrc = X + ((size_t)b * Tt + crow[rl]) * Dd + xf4 * 4;
        // Xc row = compacted position r0+xrow (rows >= count hold junk, never read)
        _Float16* xcdst = Xc + ((size_t)b * Tt + r0 + xrow) * Dd + xf4 * 4;

        f4 acc[2][8];
#pragma unroll
        for (int i = 0; i < 2; i++)
#pragma unroll
            for (int j = 0; j < 8; j++) {
                f4 z = {0.f, 0.f, 0.f, 0.f};
                acc[i][j] = z;
            }

        // ---- prologue: W_0 DMA -> bufW0; X_0 -> LDS+Xc; X_1 -> regs ----
        __builtin_amdgcn_sched_barrier(0);
#pragma unroll
        for (int j = 0; j < 2; j++)
            GLOAD_LDS16(W16 + wsrcoff[j], lds + wldsoff + j * 16384);
        __builtin_amdgcn_sched_barrier(0);
        float4 x0 = *(const float4*)(xsrc);
        float4 xu = *(const float4*)(xsrc + 32);
        __builtin_amdgcn_sched_barrier(0);
        {
            h4v hv = cvt4s(x0);        // compiler's x0-wait also drains W DMAs (in-order)
            *(h4v*)(lds + 65536 + xoff) = hv;
            *(h4v*)(xcdst) = hv;
        }
        asm volatile("s_waitcnt vmcnt(2) lgkmcnt(0)" ::: "memory");
        __builtin_amdgcn_sched_barrier(0);
        __builtin_amdgcn_s_barrier();
        __builtin_amdgcn_sched_barrier(0);

#pragma unroll 2
        for (int t = 0; t < 16; ++t) {
            const int cur = t & 1;
            const int kW = (t < 15 ? t + 1 : 15) * 32;  // halfs (tail: dead re-stage)
            const int kX = (t < 14 ? t + 2 : 15) * 32;  // floats (tail: dead load)

            // ---- issue W_{t+1} DMA into bufW[cur^1], then X_{t+2} load ----
            char* bufWn = lds + (cur ^ 1) * 32768;
            __builtin_amdgcn_sched_barrier(0);
#pragma unroll
            for (int j = 0; j < 2; j++)
                GLOAD_LDS16(W16 + wsrcoff[j] + kW, bufWn + wldsoff + j * 16384);
            __builtin_amdgcn_sched_barrier(0);
            float4 xn = *(const float4*)(xsrc + kX);
            __builtin_amdgcn_sched_barrier(0);

            // ---- compute tile t from buf[cur] ----
            const char* bW = lds + cur * 32768;
            const char* bX = lds + 65536 + cur * 8192;
            h8 a[2];
#pragma unroll
            for (int mr = 0; mr < 2; mr++) {
                int row = wm * 32 + mr * 16 + l16;
                a[mr] = *(const h8*)(bX + row * 64 + ((khi ^ ((row >> 1) & 3)) << 4));
            }
#pragma unroll
            for (int nr = 0; nr < 8; nr++) {
                int row = wn * 128 + nr * 16 + l16;
                h8 bf = *(const h8*)(bW + row * 64 + ((khi ^ ((row >> 1) & 3)) << 4));
                acc[0][nr] = __builtin_amdgcn_mfma_f32_16x16x32_f16(a[0], bf, acc[0][nr], 0, 0, 0);
                acc[1][nr] = __builtin_amdgcn_mfma_f32_16x16x32_f16(a[1], bf, acc[1][nr], 0, 0, 0);
            }

            // ---- write X_{t+1} (regs xu) into bufX[cur^1] and Xc ----
            {
                h4v hv = cvt4s(xu);
                *(h4v*)(lds + 65536 + (cur ^ 1) * 8192 + xoff) = hv;
                const int kst = (t < 15 ? t + 1 : 15) * 32;   // tail: same data rewrite
                *(h4v*)(xcdst + kst) = hv;
            }
            // Queue: [ST(t-1), W1, W2, Xload, ST(t)] -> vmcnt(2) certifies the
            // W-DMAs (and the old store), keeps {Xload, ST} in flight.
            asm volatile("s_waitcnt vmcnt(2) lgkmcnt(0)" ::: "memory");
            __builtin_amdgcn_sched_barrier(0);
            __builtin_amdgcn_s_barrier();
            __builtin_amdgcn_sched_barrier(0);
            xu = xn;
        }

        // ---- epilogue: relu * colt, reduce over N ----
        float rs[2][4];
#pragma unroll
        for (int mr = 0; mr < 2; mr++)
#pragma unroll
            for (int r = 0; r < 4; r++) rs[mr][r] = 0.f;
#pragma unroll
        for (int nr = 0; nr < 8; nr++) {
            float cv = colt[b * Hh + wn * 128 + nr * 16 + l16];
#pragma unroll
            for (int mr = 0; mr < 2; mr++)
#pragma unroll
                for (int r = 0; r < 4; r++)
                    rs[mr][r] += fmaxf(acc[mr][nr][r], 0.f) * cv;
        }
#pragma unroll
        for (int mr = 0; mr < 2; mr++)
#pragma unroll
            for (int r = 0; r < 4; r++) {
                float v = rs[mr][r];
                v += __shfl_xor(v, 1);
                v += __shfl_xor(v, 2);
                v += __shfl_xor(v, 4);
                v += __shfl_xor(v, 8);
                rs[mr][r] = v;
            }
        if (l16 == 0) {
#pragma unroll
            for (int mr = 0; mr < 2; mr++)
#pragma unroll
                for (int r = 0; r < 4; r++)
                    sred[wn][wm * 32 + mr * 16 + khi * 4 + r] = rs[mr][r];
        }
        __syncthreads();
        if (tid < 128) {
            int r = r0 + tid;
            if (r < count) {
                float s = sred[0][tid] + sred[1][tid] + sred[2][tid] + sred[3][tid];
                scores[(size_t)b * Tt + crow[r]] = s;  // mask==1 here
            }
        }
        __syncthreads();   // protect sred/bufX before next work-list iteration
    }
}

// ---------------- kernel 3: masked softmax per b (IN-PLACE) + copy col -------
// Masked entries read -1e30 (scores buffer holds junk there); exp -> 0.
__global__ void softmax_kernel(const float* __restrict__ scores, const int* __restrict__ mask,
                               const float* __restrict__ col,
                               float* __restrict__ attn, float* __restrict__ out) {
    __shared__ float sm[256];
    int b = blockIdx.x, tid = threadIdx.x;
    const float* srow = scores + (size_t)b * Tt;
    const int* mrow = mask + (size_t)b * Tt;
    float v[8];
#pragma unroll
    for (int i = 0; i < 8; i++)
        v[i] = mrow[tid + i * 256] ? srow[tid + i * 256] : -1e30f;
    float mx = -1e30f;
#pragma unroll
    for (int i = 0; i < 8; i++) mx = fmaxf(mx, v[i]);
    sm[tid] = mx;
    __syncthreads();
    for (int s = 128; s > 0; s >>= 1) {
        if (tid < s) sm[tid] = fmaxf(sm[tid], sm[tid + s]);
        __syncthreads();
    }
    float M = sm[0];
    __syncthreads();
    float e[8];
    float sum = 0.f;
#pragma unroll
    for (int i = 0; i < 8; i++) {
        e[i] = __expf(v[i] - M);
        sum += e[i];
    }
    sm[tid] = sum;
    __syncthreads();
    for (int s = 128; s > 0; s >>= 1) {
        if (tid < s) sm[tid] += sm[tid + s];
        __syncthreads();
    }
    float inv = 1.f / sm[0];
    float* arow = attn + (size_t)b * Tt;
#pragma unroll
    for (int i = 0; i < 8; i++) arow[tid + i * 256] = e[i] * inv;
    for (int d = tid; d < Dd; d += 256) out[(size_t)b * 1024 + d] = col[(size_t)b * Dd + d];
}

// ---------------- kernel 4: weighted sums over DENSE fp16 compacted X --------
// Thread (cg=tid&63, rs=tid>>6): cols cg*8..+8, rows j==rs mod 4. h8 loads,
// LDS reduce across rs. Rows >= count never touched (sa loop bound = lim).
__global__ __launch_bounds__(256) void wsum_kernel(
    const float* __restrict__ attn, const _Float16* __restrict__ Xc,
    const int* __restrict__ cidx, const int* __restrict__ cnt,
    float* __restrict__ part) {
    int tc = blockIdx.x;   // 0..3
    int b  = blockIdx.y;   // 0..127
    int tid = threadIdx.x; // 256
    int count = cnt[b];
    int base = tc * 512;
    int lim = count - base; if (lim > 512) lim = 512; if (lim < 0) lim = 0;
    __shared__ float sa[512];
    __shared__ float red[4][512];
    const int* crow = cidx + (size_t)b * Tt;
    for (int j = tid; j < 512; j += 256) {
        int r = base + j;
        sa[j] = (r < count) ? attn[(size_t)b * Tt + crow[r]] : 0.f;
    }
    __syncthreads();
    const int cg = tid & 63, rs = tid >> 6;
    float acc[8];
#pragma unroll
    for (int e = 0; e < 8; e++) acc[e] = 0.f;
    const _Float16* xb = Xc + ((size_t)b * Tt + base) * Dd + cg * 8;
    for (int j = rs; j < lim; j += 4) {
        h8 xv = *(const h8*)(xb + (size_t)j * Dd);
        float s = sa[j];
#pragma unroll
        for (int e = 0; e < 8; e++) acc[e] += s * (float)xv[e];
    }
#pragma unroll
    for (int e = 0; e < 8; e++) red[rs][cg * 8 + e] = acc[e];
    __syncthreads();
    for (int d = tid; d < Dd; d += 256)
        part[((size_t)b * 4 + tc) * Dd + d] = red[0][d] + red[1][d] + red[2][d] + red[3][d];
}

// ---------------- kernel 5: combine partials, write both outputs ----------------
__global__ void combine_kernel(const float* __restrict__ part, float* __restrict__ out) {
    int i = blockIdx.x * 256 + threadIdx.x;  // < 65536
    int b = i >> 9, d = i & 511;
    float s = 0.f;
#pragma unroll
    for (int tc = 0; tc < 4; tc++) s += part[((size_t)b * 4 + tc) * Dd + d];
    out[(size_t)b * 1024 + 512 + d] = s;                 // cat section, second half
    out[(size_t)Bb * 1024 + (size_t)b * 512 + d] = s;    // attention_output section
}

extern "C" void kernel_launch(void* const* d_in, const int* in_sizes, int n_in,
                              void* d_out, int out_size, void* d_ws, size_t ws_size,
                              hipStream_t stream) {
    const float* col  = (const float*)d_in[0];   // [128,512]
    const float* X    = (const float*)d_in[1];   // [128,2048,512]
    const int*   mask = (const int*)d_in[2];     // [128,2048]
    const float* W    = (const float*)d_in[3];   // [512,512]
    float* out = (float*)d_out;

    char* ws = (char*)d_ws;
    _Float16* W16   = (_Float16*)ws;                     // 0    .. 512K
    float*    colt  = (float*)(ws + (512 << 10));        // 512K .. 768K
    float*    scores= (float*)(ws + (768 << 10));        // 768K .. 1792K
    float*    attn  = scores;                            // softmax in-place
    float*    part  = (float*)(ws + (1792 << 10));       // 1792K.. 2816K
    int*      cidx  = (int*)(ws + (2816 << 10));         // 2816K.. 3840K
    int*      cnt   = (int*)(ws + (3840 << 10));         // 3840K.. +512B
    int*      tlist = (int*)(ws + (3841 << 10));         // 3841K.. +16KB
    int*      ntile = (int*)(ws + (3860 << 10));         // 3860K.. +4B
    _Float16* Xc    = (_Float16*)(ws + (4096 << 10));    // 4M .. 272M (compacted fp16 X)

    hipMemsetAsync(ntile, 0, 4, stream);
    hipLaunchKernelGGL(prep_kernel, dim3(1408), dim3(256), 0, stream,
                       W, W16, mask, cidx, cnt, tlist, ntile, col, colt);
    hipLaunchKernelGGL(scores_kernel, dim3(NG), dim3(1024), 0, stream,
                       X, W16, colt, cidx, cnt, tlist, ntile, scores, Xc);
    hipLaunchKernelGGL(softmax_kernel, dim3(Bb), dim3(256), 0, stream, scores, mask, col, attn, out);
    hipLaunchKernelGGL(wsum_kernel, dim3(4, Bb), dim3(256), 0, stream, attn, Xc, cidx, cnt, part);
    hipLaunchKernelGGL(combine_kernel, dim3(65536 / 256), dim3(256), 0, stream, part, out);
}

// Round 12
// 274.362 us; speedup vs baseline: 1.3072x; 1.0015x over previous
//
#include <hip/hip_runtime.h>
#include <cstdint>
#include <cstddef>

#define Bb 128
#define Tt 2048
#define Dd 512
#define Hh 512
#define Mtot (Bb*Tt)
#define NG 1152   // scores grid; grid-stride covers pathological masks

typedef __attribute__((ext_vector_type(8))) _Float16 h8;
typedef __attribute__((ext_vector_type(4))) _Float16 h4v;
typedef __attribute__((ext_vector_type(4))) float f4;

// Direct global->LDS DMA, 16B per lane. LDS dest is WAVE-UNIFORM base; HW
// writes lane l at base + l*16. Global src is per-lane (pre-swizzled).
#define GLOAD_LDS16(gsrc, ldst) \
    __builtin_amdgcn_global_load_lds((const __attribute__((address_space(1))) void*)(gsrc), \
                                     (__attribute__((address_space(3))) void*)(ldst), 16, 0, 0)

__device__ __forceinline__ h4v cvt4s(const float4 a) {
    h4v h;
    h[0] = (_Float16)a.x; h[1] = (_Float16)a.y;
    h[2] = (_Float16)a.z; h[3] = (_Float16)a.w;
    return h;
}

// ---------------- kernel 1: fused prep ----------------
__global__ __launch_bounds__(256) void prep_kernel(
    const float* __restrict__ W, _Float16* __restrict__ W16,
    const int* __restrict__ mask, int* __restrict__ cidx, int* __restrict__ cnt,
    int* __restrict__ tlist, int* __restrict__ ntiles,
    const float* __restrict__ col, float* __restrict__ colt)
{
    const int blk = blockIdx.x, tid = threadIdx.x;
    if (blk < 1024) {                       // ---- W16 cast ----
        int i = blk * 256 + tid;
        W16[i] = (_Float16)W[i];
        return;
    }
    if (blk < 1152) {                       // ---- compaction (b = blk-1024) ----
        __shared__ int wsum[4];
        int b = blk - 1024;
        const int* mrow = mask + (size_t)b * Tt;
        int mv[8], c = 0;
#pragma unroll
        for (int i = 0; i < 8; i++) {
            mv[i] = mrow[tid * 8 + i];
            c += mv[i];
        }
        int lane = tid & 63, wv = tid >> 6;
        int inc = c;
#pragma unroll
        for (int off = 1; off < 64; off <<= 1) {
            int n = __shfl_up(inc, off);
            if (lane >= off) inc += n;
        }
        if (lane == 63) wsum[wv] = inc;
        __syncthreads();
        int wbase = 0;
        for (int w = 0; w < wv; w++) wbase += wsum[w];
        int pos = wbase + inc - c;          // exclusive prefix
        int* crow = cidx + (size_t)b * Tt;
#pragma unroll
        for (int i = 0; i < 8; i++)
            if (mv[i]) crow[pos++] = tid * 8 + i;
        if (tid == 255) {
            int total = wbase + inc;
            cnt[b] = total;
            int nt = (total + 127) >> 7;    // tiles of 128 rows
            int base = atomicAdd(ntiles, nt);
            for (int i = 0; i < nt; i++) tlist[base + i] = (b << 8) | i;
        }
        return;
    }
    {                                        // ---- col_proj ----
        __shared__ float c[Dd];
        int idx = blk - 1152;
        int b = idx >> 1;
        int h = (idx & 1) * 256 + tid;
        c[tid] = col[b * Dd + tid];
        c[tid + 256] = col[b * Dd + 256 + tid];
        __syncthreads();
        const f4* w4 = (const f4*)(W + (size_t)h * Dd);
        float acc = 0.f;
#pragma unroll 8
        for (int k = 0; k < Dd / 4; k++) {
            f4 w = w4[k];
            acc += w.x * c[4 * k] + w.y * c[4 * k + 1] + w.z * c[4 * k + 2] + w.w * c[4 * k + 3];
        }
        colt[b * Hh + h] = fmaxf(acc, 0.f);
    }
}

// ---------------- kernel 2: scores GEMM, 3-buffer W pipeline ----------------
// BM=128, BN=512, BK=32, 16 K-steps, 16 waves = 4M x 4N, wave tile 32x128.
// W TRIPLE-buffered: step t issues W(t+2) -> ~2 full steps of DMA latency
// cover before the barrier that certifies it. Per-step issue order (pinned):
// [Xload(t+2), W(t+2)a, W(t+2)b]. FIFO audit:
//   entering step t: [X(t+1), W(t+1)a, W(t+1)b]
//   after issues:    [X(t+1), W(t+1)a, W(t+1)b, X(t+2), W(t+2)a, W(t+2)b]
//   cvt(xu=X(t+1)) waits X(t+1) only (queue head; X issued BEFORE W(t+1))
//   pre-barrier vmcnt(3): retires W(t+1)a/b; leaves [X(t+2), W(t+2)a/b]  ✓
// Prologue: issues X0,X1 then W0,W1; cvt(x0) retires X0; vmcnt(2) retires
// X1+W0a/b (certify W0), leaves [W1a,W1b]; also drains any stale DMAs from a
// previous grid-stride tile (vmcnt is count-based).
// LDS: bufW 3x32KB @0/32768/65536; bufX 2x8KB @98304/106496; sred @114688.
__global__ __launch_bounds__(1024, 4) void scores_kernel(
    const float* __restrict__ X,        // [B*T][512]
    const _Float16* __restrict__ W16,   // [512][512]
    const float* __restrict__ colt,     // [128][512]
    const int* __restrict__ cidx,       // [B][T]
    const int* __restrict__ cnt,        // [B]
    const int* __restrict__ tlist,      // work list: (b<<8)|tile
    const int* __restrict__ ntiles,     // [1]
    float* __restrict__ scores)         // [B*T] (masked entries untouched)
{
    const int tid = threadIdx.x;
    const int total = ntiles[0];

    __shared__ __align__(16) char lds[116736];
    float (*sred)[128] = (float(*)[128])(lds + 114688);

    const int wave = tid >> 6;
    const int lane = tid & 63;
    const int wm = wave >> 2;   // 0..3 : M quarter (rows wm*32..+32)
    const int wn = wave & 3;    // 0..3 : N strip (cols wn*128..+128)
    const int l16 = lane & 15;
    const int khi = lane >> 4;  // 0..3

    int wsrcoff[2];
#pragma unroll
    for (int j = 0; j < 2; j++) {
        int r = (j * 16 + wave) * 16 + (lane >> 2);
        int c = (lane & 3) ^ ((r >> 1) & 3);
        wsrcoff[j] = r * Dd + c * 8;
    }
    const int wldsoff = wave * 1024;   // + j*16384 per chunk-call

    const int xrow = tid >> 3, xf4 = tid & 7;
    const int xoff = xrow * 64 + (((xf4 >> 1) ^ ((xrow >> 1) & 3)) << 4) + (xf4 & 1) * 8;

    for (int idx = blockIdx.x; idx < total; idx += NG) {
        const int ent = tlist[idx];
        const int b = ent >> 8;
        const int tile = ent & 255;
        const int count = cnt[b];
        const int r0 = tile * 128;

        const int* crow = cidx + (size_t)b * Tt;
        int rl = r0 + xrow; if (rl >= count) rl = count - 1;  // clamp (dup, never stored)
        const float* xsrc = X + ((size_t)b * Tt + crow[rl]) * Dd + xf4 * 4;

        f4 acc[2][8];
#pragma unroll
        for (int i = 0; i < 2; i++)
#pragma unroll
            for (int j = 0; j < 8; j++) {
                f4 z = {0.f, 0.f, 0.f, 0.f};
                acc[i][j] = z;
            }

        // ---- prologue: X0,X1 loads; W0 -> buf0, W1 -> buf1 ----
        __builtin_amdgcn_sched_barrier(0);
        float4 x0 = *(const float4*)(xsrc);
        float4 xu = *(const float4*)(xsrc + 32);
        __builtin_amdgcn_sched_barrier(0);
#pragma unroll
        for (int j = 0; j < 2; j++)
            GLOAD_LDS16(W16 + wsrcoff[j], lds + wldsoff + j * 16384);
#pragma unroll
        for (int j = 0; j < 2; j++)
            GLOAD_LDS16(W16 + wsrcoff[j] + 32, lds + 32768 + wldsoff + j * 16384);
        __builtin_amdgcn_sched_barrier(0);
        {
            h4v hv = cvt4s(x0);            // waits X0 only (queue head)
            *(h4v*)(lds + 98304 + xoff) = hv;
        }
        asm volatile("s_waitcnt vmcnt(2) lgkmcnt(0)" ::: "memory");  // certify W0; leave [W1a,W1b]
        __builtin_amdgcn_sched_barrier(0);
        __builtin_amdgcn_s_barrier();
        __builtin_amdgcn_sched_barrier(0);

        int wc = 0, wp = 2;   // compute buffer = t%3, prefetch dest = (t+2)%3
#pragma unroll 4
        for (int t = 0; t < 16; ++t) {
            const int cur = t & 1;
            const int kP = (t < 14 ? t + 2 : 15) * 32;  // t+2 prefetch (tail: dead re-stage)

            // ---- issue: Xload(t+2) FIRST, then W(t+2) DMAs ----
            __builtin_amdgcn_sched_barrier(0);
            float4 xn = *(const float4*)(xsrc + kP);
            __builtin_amdgcn_sched_barrier(0);
            char* bufWn = lds + wp * 32768;
#pragma unroll
            for (int j = 0; j < 2; j++)
                GLOAD_LDS16(W16 + wsrcoff[j] + kP, bufWn + wldsoff + j * 16384);
            __builtin_amdgcn_sched_barrier(0);

            // ---- compute tile t from bufW[wc], bufX[cur] ----
            const char* bW = lds + wc * 32768;
            const char* bX = lds + 98304 + cur * 8192;
            h8 a[2];
#pragma unroll
            for (int mr = 0; mr < 2; mr++) {
                int row = wm * 32 + mr * 16 + l16;
                a[mr] = *(const h8*)(bX + row * 64 + ((khi ^ ((row >> 1) & 3)) << 4));
            }
#pragma unroll
            for (int nr = 0; nr < 8; nr++) {
                int row = wn * 128 + nr * 16 + l16;
                h8 bf = *(const h8*)(bW + row * 64 + ((khi ^ ((row >> 1) & 3)) << 4));
                acc[0][nr] = __builtin_amdgcn_mfma_f32_16x16x32_f16(a[0], bf, acc[0][nr], 0, 0, 0);
                acc[1][nr] = __builtin_amdgcn_mfma_f32_16x16x32_f16(a[1], bf, acc[1][nr], 0, 0, 0);
            }

            // ---- write X(t+1) (regs xu) into bufX[cur^1] ----
            {
                h4v hv = cvt4s(xu);        // waits X(t+1) only (queue head)
                *(h4v*)(lds + 98304 + (cur ^ 1) * 8192 + xoff) = hv;
            }
            // vmcnt(3): retire W(t+1)a/b (certify for step t+1); leave
            // [X(t+2), W(t+2)a, W(t+2)b] in flight across the barrier.
            asm volatile("s_waitcnt vmcnt(3) lgkmcnt(0)" ::: "memory");
            __builtin_amdgcn_sched_barrier(0);
            __builtin_amdgcn_s_barrier();
            __builtin_amdgcn_sched_barrier(0);
            xu = xn;
            wc = (wc == 2) ? 0 : wc + 1;
            wp = (wp == 2) ? 0 : wp + 1;
        }

        // ---- epilogue: relu * colt, reduce over N ----
        float rs[2][4];
#pragma unroll
        for (int mr = 0; mr < 2; mr++)
#pragma unroll
            for (int r = 0; r < 4; r++) rs[mr][r] = 0.f;
#pragma unroll
        for (int nr = 0; nr < 8; nr++) {
            float cv = colt[b * Hh + wn * 128 + nr * 16 + l16];
#pragma unroll
            for (int mr = 0; mr < 2; mr++)
#pragma unroll
                for (int r = 0; r < 4; r++)
                    rs[mr][r] += fmaxf(acc[mr][nr][r], 0.f) * cv;
        }
#pragma unroll
        for (int mr = 0; mr < 2; mr++)
#pragma unroll
            for (int r = 0; r < 4; r++) {
                float v = rs[mr][r];
                v += __shfl_xor(v, 1);
                v += __shfl_xor(v, 2);
                v += __shfl_xor(v, 4);
                v += __shfl_xor(v, 8);
                rs[mr][r] = v;
            }
        if (l16 == 0) {
#pragma unroll
            for (int mr = 0; mr < 2; mr++)
#pragma unroll
                for (int r = 0; r < 4; r++)
                    sred[wn][wm * 32 + mr * 16 + khi * 4 + r] = rs[mr][r];
        }
        __syncthreads();
        if (tid < 128) {
            int r = r0 + tid;
            if (r < count) {
                float s = sred[0][tid] + sred[1][tid] + sred[2][tid] + sred[3][tid];
                scores[(size_t)b * Tt + crow[r]] = s;  // mask==1 here
            }
        }
        __syncthreads();   // protect sred/bufX before next work-list iteration
    }
}

// ---------------- kernel 3: masked softmax per b (IN-PLACE) + copy col -------
__global__ void softmax_kernel(const float* __restrict__ scores, const int* __restrict__ mask,
                               const float* __restrict__ col,
                               float* __restrict__ attn, float* __restrict__ out) {
    __shared__ float sm[256];
    int b = blockIdx.x, tid = threadIdx.x;
    const float* srow = scores + (size_t)b * Tt;
    const int* mrow = mask + (size_t)b * Tt;
    float v[8];
#pragma unroll
    for (int i = 0; i < 8; i++)
        v[i] = mrow[tid + i * 256] ? srow[tid + i * 256] : -1e30f;
    float mx = -1e30f;
#pragma unroll
    for (int i = 0; i < 8; i++) mx = fmaxf(mx, v[i]);
    sm[tid] = mx;
    __syncthreads();
    for (int s = 128; s > 0; s >>= 1) {
        if (tid < s) sm[tid] = fmaxf(sm[tid], sm[tid + s]);
        __syncthreads();
    }
    float M = sm[0];
    __syncthreads();
    float e[8];
    float sum = 0.f;
#pragma unroll
    for (int i = 0; i < 8; i++) {
        e[i] = __expf(v[i] - M);
        sum += e[i];
    }
    sm[tid] = sum;
    __syncthreads();
    for (int s = 128; s > 0; s >>= 1) {
        if (tid < s) sm[tid] += sm[tid + s];
        __syncthreads();
    }
    float inv = 1.f / sm[0];
    float* arow = attn + (size_t)b * Tt;
#pragma unroll
    for (int i = 0; i < 8; i++) arow[tid + i * 256] = e[i] * inv;
    for (int d = tid; d < Dd; d += 256) out[(size_t)b * 1024 + d] = col[(size_t)b * Dd + d];
}

// ---------------- kernel 4: weighted sums over COMPACTED t (R9 version) ------
__global__ void wsum_kernel(const float* __restrict__ attn, const float* __restrict__ X,
                            const int* __restrict__ cidx, const int* __restrict__ cnt,
                            float* __restrict__ part) {
    int dh = blockIdx.x;   // 0..1
    int tc = blockIdx.y;   // 0..3
    int b  = blockIdx.z;   // 0..127
    int tid = threadIdx.x; // 256
    int d = dh * 256 + tid;
    int count = cnt[b];
    int base = tc * 512;
    int lim = count - base; if (lim > 512) lim = 512; if (lim < 0) lim = 0;
    __shared__ float sa[512];
    __shared__ int  sidx[512];
    const int* crow = cidx + (size_t)b * Tt;
    for (int j = tid; j < 512; j += 256) {
        int r = base + j;
        bool v = r < count;
        int t = v ? crow[r] : 0;
        sidx[j] = t;
        sa[j] = v ? attn[(size_t)b * Tt + t] : 0.f;
    }
    __syncthreads();
    float acc = 0.f;
    const float* xb = X + (size_t)b * Tt * Dd + d;
#pragma unroll 4
    for (int j = 0; j < lim; j++) acc += sa[j] * xb[(size_t)sidx[j] * Dd];
    part[((size_t)b * 4 + tc) * Dd + d] = acc;
}

// ---------------- kernel 5: combine partials, write both outputs ----------------
__global__ void combine_kernel(const float* __restrict__ part, float* __restrict__ out) {
    int i = blockIdx.x * 256 + threadIdx.x;  // < 65536
    int b = i >> 9, d = i & 511;
    float s = 0.f;
#pragma unroll
    for (int tc = 0; tc < 4; tc++) s += part[((size_t)b * 4 + tc) * Dd + d];
    out[(size_t)b * 1024 + 512 + d] = s;                 // cat section, second half
    out[(size_t)Bb * 1024 + (size_t)b * 512 + d] = s;    // attention_output section
}

extern "C" void kernel_launch(void* const* d_in, const int* in_sizes, int n_in,
                              void* d_out, int out_size, void* d_ws, size_t ws_size,
                              hipStream_t stream) {
    const float* col  = (const float*)d_in[0];   // [128,512]
    const float* X    = (const float*)d_in[1];   // [128,2048,512]
    const int*   mask = (const int*)d_in[2];     // [128,2048]
    const float* W    = (const float*)d_in[3];   // [512,512]
    float* out = (float*)d_out;

    char* ws = (char*)d_ws;
    _Float16* W16   = (_Float16*)ws;                     // 0    .. 512K
    float*    colt  = (float*)(ws + (512 << 10));        // 512K .. 768K
    float*    scores= (float*)(ws + (768 << 10));        // 768K .. 1792K
    float*    attn  = scores;                            // softmax in-place
    float*    part  = (float*)(ws + (1792 << 10));       // 1792K.. 2816K
    int*      cidx  = (int*)(ws + (2816 << 10));         // 2816K.. 3840K
    int*      cnt   = (int*)(ws + (3840 << 10));         // 3840K.. +512B
    int*      tlist = (int*)(ws + (3841 << 10));         // 3841K.. +16KB
    int*      ntile = (int*)(ws + (3860 << 10));         // 3860K.. +4B

    hipMemsetAsync(ntile, 0, 4, stream);
    hipLaunchKernelGGL(prep_kernel, dim3(1408), dim3(256), 0, stream,
                       W, W16, mask, cidx, cnt, tlist, ntile, col, colt);
    hipLaunchKernelGGL(scores_kernel, dim3(NG), dim3(1024), 0, stream,
                       X, W16, colt, cidx, cnt, tlist, ntile, scores);
    hipLaunchKernelGGL(softmax_kernel, dim3(Bb), dim3(256), 0, stream, scores, mask, col, attn, out);
    hipLaunchKernelGGL(wsum_kernel, dim3(2, 4, Bb), dim3(256), 0, stream, attn, X, cidx, cnt, part);
    hipLaunchKernelGGL(combine_kernel, dim3(65536 / 256), dim3(256), 0, stream, part, out);
}

// Round 13
// 244.547 us; speedup vs baseline: 1.4666x; 1.1219x over previous
//
#include <hip/hip_runtime.h>
#include <cstdint>
#include <cstddef>

#define Bb 128
#define Tt 2048
#define Dd 512
#define Hh 512
#define Mtot (Bb*Tt)
#define NG 1152   // scores grid; grid-stride covers pathological masks

typedef __attribute__((ext_vector_type(8))) _Float16 h8;
typedef __attribute__((ext_vector_type(4))) _Float16 h4v;
typedef __attribute__((ext_vector_type(4))) float f4;

// Direct global->LDS DMA, 16B per lane. LDS dest is WAVE-UNIFORM base; HW
// writes lane l at base + l*16. Global src is per-lane (pre-swizzled).
#define GLOAD_LDS16(gsrc, ldst) \
    __builtin_amdgcn_global_load_lds((const __attribute__((address_space(1))) void*)(gsrc), \
                                     (__attribute__((address_space(3))) void*)(ldst), 16, 0, 0)

__device__ __forceinline__ h4v cvt4s(const float4 a) {
    h4v h;
    h[0] = (_Float16)a.x; h[1] = (_Float16)a.y;
    h[2] = (_Float16)a.z; h[3] = (_Float16)a.w;
    return h;
}

// ---------------- kernel 1: fused prep ----------------
__global__ __launch_bounds__(256) void prep_kernel(
    const float* __restrict__ W, _Float16* __restrict__ W16,
    const int* __restrict__ mask, int* __restrict__ cidx, int* __restrict__ cnt,
    int* __restrict__ tlist, int* __restrict__ ntiles,
    const float* __restrict__ col, float* __restrict__ colt)
{
    const int blk = blockIdx.x, tid = threadIdx.x;
    if (blk < 1024) {                       // ---- W16 cast ----
        int i = blk * 256 + tid;
        W16[i] = (_Float16)W[i];
        return;
    }
    if (blk < 1152) {                       // ---- compaction (b = blk-1024) ----
        __shared__ int wsum[4];
        int b = blk - 1024;
        const int* mrow = mask + (size_t)b * Tt;
        int mv[8], c = 0;
#pragma unroll
        for (int i = 0; i < 8; i++) {
            mv[i] = mrow[tid * 8 + i];
            c += mv[i];
        }
        int lane = tid & 63, wv = tid >> 6;
        int inc = c;
#pragma unroll
        for (int off = 1; off < 64; off <<= 1) {
            int n = __shfl_up(inc, off);
            if (lane >= off) inc += n;
        }
        if (lane == 63) wsum[wv] = inc;
        __syncthreads();
        int wbase = 0;
        for (int w = 0; w < wv; w++) wbase += wsum[w];
        int pos = wbase + inc - c;          // exclusive prefix
        int* crow = cidx + (size_t)b * Tt;
#pragma unroll
        for (int i = 0; i < 8; i++)
            if (mv[i]) crow[pos++] = tid * 8 + i;
        if (tid == 255) {
            int total = wbase + inc;
            cnt[b] = total;
            int nt = (total + 127) >> 7;    // tiles of 128 rows
            int base = atomicAdd(ntiles, nt);
            for (int i = 0; i < nt; i++) tlist[base + i] = (b << 8) | i;
        }
        return;
    }
    {                                        // ---- col_proj ----
        __shared__ float c[Dd];
        int idx = blk - 1152;
        int b = idx >> 1;
        int h = (idx & 1) * 256 + tid;
        c[tid] = col[b * Dd + tid];
        c[tid + 256] = col[b * Dd + 256 + tid];
        __syncthreads();
        const f4* w4 = (const f4*)(W + (size_t)h * Dd);
        float acc = 0.f;
#pragma unroll 8
        for (int k = 0; k < Dd / 4; k++) {
            f4 w = w4[k];
            acc += w.x * c[4 * k] + w.y * c[4 * k + 1] + w.z * c[4 * k + 2] + w.w * c[4 * k + 3];
        }
        colt[b * Hh + h] = fmaxf(acc, 0.f);
    }
}

// ---------------- kernel 2: scores GEMM, R9 pipeline, 2M x 8N wave split -----
// BM=128, BN=512, BK=32, 16 K-steps, 16 waves. CHANGE vs R9: waves split
// 2M x 8N -> wave tile 64x64 (square) instead of 4M x 4N's 32x128.
// LDS read traffic per block-step: 16 x (Mw+Nw)/16 KB = 128 KB vs 160 KB
// (-20%) -- we measured ~70% LDS-BW utilization, so traffic is the lever.
// acc f4[4][4] (64 regs, same as R9), same staging, same 80KB dbuf layout
// (2 blocks/CU), same vmcnt(1) audit: per-step queue after cvt(X(t+1)) is
// [Wa(t+1), Wb(t+1), X(t+2)] -> vmcnt(1) certifies both W-DMAs.
__global__ __launch_bounds__(1024, 4) void scores_kernel(
    const float* __restrict__ X,        // [B*T][512]
    const _Float16* __restrict__ W16,   // [512][512]
    const float* __restrict__ colt,     // [128][512]
    const int* __restrict__ cidx,       // [B][T]
    const int* __restrict__ cnt,        // [B]
    const int* __restrict__ tlist,      // work list: (b<<8)|tile
    const int* __restrict__ ntiles,     // [1]
    float* __restrict__ scores)         // [B*T] (masked entries untouched)
{
    const int tid = threadIdx.x;
    const int total = ntiles[0];

    // LDS: bufW 2x32KB @0/32768; bufX 2x8KB @65536/73728; sred[8][128] (4KB)
    // aliases bufX[0] (written only after the final barrier). Total 80KB.
    __shared__ __align__(16) char lds[81920];
    float (*sred)[128] = (float(*)[128])(lds + 65536);

    const int wave = tid >> 6;
    const int lane = tid & 63;
    const int wm = wave >> 3;   // 0..1 : M half (rows wm*64..+64)
    const int wn = wave & 7;    // 0..7 : N strip (cols wn*64..+64)
    const int l16 = lane & 15;
    const int khi = lane >> 4;  // 0..3

    int wsrcoff[2];
#pragma unroll
    for (int j = 0; j < 2; j++) {
        int r = (j * 16 + wave) * 16 + (lane >> 2);
        int c = (lane & 3) ^ ((r >> 1) & 3);
        wsrcoff[j] = r * Dd + c * 8;
    }
    const int wldsoff = wave * 1024;   // + j*16384 per chunk-call

    const int xrow = tid >> 3, xf4 = tid & 7;
    const int xoff = xrow * 64 + (((xf4 >> 1) ^ ((xrow >> 1) & 3)) << 4) + (xf4 & 1) * 8;

    for (int idx = blockIdx.x; idx < total; idx += NG) {
        const int ent = tlist[idx];
        const int b = ent >> 8;
        const int tile = ent & 255;
        const int count = cnt[b];
        const int r0 = tile * 128;

        const int* crow = cidx + (size_t)b * Tt;
        int rl = r0 + xrow; if (rl >= count) rl = count - 1;  // clamp (dup, never stored)
        const float* xsrc = X + ((size_t)b * Tt + crow[rl]) * Dd + xf4 * 4;

        f4 acc[4][4];
#pragma unroll
        for (int i = 0; i < 4; i++)
#pragma unroll
            for (int j = 0; j < 4; j++) {
                f4 z = {0.f, 0.f, 0.f, 0.f};
                acc[i][j] = z;
            }

        // ---- prologue: W_0 DMA -> bufW0; X_0 -> LDS; X_1 -> regs ----
        __builtin_amdgcn_sched_barrier(0);
#pragma unroll
        for (int j = 0; j < 2; j++)
            GLOAD_LDS16(W16 + wsrcoff[j], lds + wldsoff + j * 16384);
        __builtin_amdgcn_sched_barrier(0);
        float4 x0 = *(const float4*)(xsrc);
        float4 xu = *(const float4*)(xsrc + 32);
        __builtin_amdgcn_sched_barrier(0);
        {
            h4v hv = cvt4s(x0);        // waits x0 -> drains W_0 DMAs too (in-order)
            *(h4v*)(lds + 65536 + xoff) = hv;
        }
        asm volatile("s_waitcnt vmcnt(1) lgkmcnt(0)" ::: "memory");
        __builtin_amdgcn_sched_barrier(0);
        __builtin_amdgcn_s_barrier();
        __builtin_amdgcn_sched_barrier(0);

#pragma unroll 2
        for (int t = 0; t < 16; ++t) {
            const int cur = t & 1;
            const int kW = (t < 15 ? t + 1 : 15) * 32;  // halfs (tail: dead re-stage)
            const int kX = (t < 14 ? t + 2 : 15) * 32;  // floats (tail: dead load)

            // ---- issue W_{t+1} DMA into bufW[cur^1], then X_{t+2} load ----
            char* bufWn = lds + (cur ^ 1) * 32768;
            __builtin_amdgcn_sched_barrier(0);
#pragma unroll
            for (int j = 0; j < 2; j++)
                GLOAD_LDS16(W16 + wsrcoff[j] + kW, bufWn + wldsoff + j * 16384);
            __builtin_amdgcn_sched_barrier(0);
            float4 xn = *(const float4*)(xsrc + kX);
            __builtin_amdgcn_sched_barrier(0);

            // ---- compute tile t from buf[cur]: wave tile 64x64 ----
            const char* bW = lds + cur * 32768;
            const char* bX = lds + 65536 + cur * 8192;
            h8 a[4];
#pragma unroll
            for (int mr = 0; mr < 4; mr++) {
                int row = wm * 64 + mr * 16 + l16;
                a[mr] = *(const h8*)(bX + row * 64 + ((khi ^ ((row >> 1) & 3)) << 4));
            }
#pragma unroll
            for (int nr = 0; nr < 4; nr++) {
                int row = wn * 64 + nr * 16 + l16;
                h8 bf = *(const h8*)(bW + row * 64 + ((khi ^ ((row >> 1) & 3)) << 4));
#pragma unroll
                for (int mr = 0; mr < 4; mr++)
                    acc[mr][nr] = __builtin_amdgcn_mfma_f32_16x16x32_f16(a[mr], bf, acc[mr][nr], 0, 0, 0);
            }

            // ---- write X(t+1) (regs xu) into bufX[cur^1] ----
            {
                h4v hv = cvt4s(xu);    // waits X(t+1) (queue head after W(t+1))
                *(h4v*)(lds + 65536 + (cur ^ 1) * 8192 + xoff) = hv;
            }
            // Queue = [Wa(t+1), Wb(t+1), X(t+2)] -> vmcnt(1) certifies the
            // W-DMAs, keeps the X prefetch in flight.
            asm volatile("s_waitcnt vmcnt(1) lgkmcnt(0)" ::: "memory");
            __builtin_amdgcn_sched_barrier(0);
            __builtin_amdgcn_s_barrier();
            __builtin_amdgcn_sched_barrier(0);
            xu = xn;
        }

        // ---- epilogue: relu * colt, reduce over N ----
        float rs[4][4];
#pragma unroll
        for (int mr = 0; mr < 4; mr++)
#pragma unroll
            for (int r = 0; r < 4; r++) rs[mr][r] = 0.f;
#pragma unroll
        for (int nr = 0; nr < 4; nr++) {
            float cv = colt[b * Hh + wn * 64 + nr * 16 + l16];
#pragma unroll
            for (int mr = 0; mr < 4; mr++)
#pragma unroll
                for (int r = 0; r < 4; r++)
                    rs[mr][r] += fmaxf(acc[mr][nr][r], 0.f) * cv;
        }
#pragma unroll
        for (int mr = 0; mr < 4; mr++)
#pragma unroll
            for (int r = 0; r < 4; r++) {
                float v = rs[mr][r];
                v += __shfl_xor(v, 1);
                v += __shfl_xor(v, 2);
                v += __shfl_xor(v, 4);
                v += __shfl_xor(v, 8);
                rs[mr][r] = v;
            }
        // C/D layout: local row = wm*64 + mr*16 + khi*4 + r; col = l16.
        if (l16 == 0) {
#pragma unroll
            for (int mr = 0; mr < 4; mr++)
#pragma unroll
                for (int r = 0; r < 4; r++)
                    sred[wn][wm * 64 + mr * 16 + khi * 4 + r] = rs[mr][r];
        }
        __syncthreads();
        if (tid < 128) {
            int r = r0 + tid;
            if (r < count) {
                float s = sred[0][tid] + sred[1][tid] + sred[2][tid] + sred[3][tid]
                        + sred[4][tid] + sred[5][tid] + sred[6][tid] + sred[7][tid];
                scores[(size_t)b * Tt + crow[r]] = s;  // mask==1 here
            }
        }
        __syncthreads();   // protect sred/bufX before next work-list iteration
    }
}

// ---------------- kernel 3: masked softmax per b (IN-PLACE) + copy col -------
__global__ void softmax_kernel(const float* __restrict__ scores, const int* __restrict__ mask,
                               const float* __restrict__ col,
                               float* __restrict__ attn, float* __restrict__ out) {
    __shared__ float sm[256];
    int b = blockIdx.x, tid = threadIdx.x;
    const float* srow = scores + (size_t)b * Tt;
    const int* mrow = mask + (size_t)b * Tt;
    float v[8];
#pragma unroll
    for (int i = 0; i < 8; i++)
        v[i] = mrow[tid + i * 256] ? srow[tid + i * 256] : -1e30f;
    float mx = -1e30f;
#pragma unroll
    for (int i = 0; i < 8; i++) mx = fmaxf(mx, v[i]);
    sm[tid] = mx;
    __syncthreads();
    for (int s = 128; s > 0; s >>= 1) {
        if (tid < s) sm[tid] = fmaxf(sm[tid], sm[tid + s]);
        __syncthreads();
    }
    float M = sm[0];
    __syncthreads();
    float e[8];
    float sum = 0.f;
#pragma unroll
    for (int i = 0; i < 8; i++) {
        e[i] = __expf(v[i] - M);
        sum += e[i];
    }
    sm[tid] = sum;
    __syncthreads();
    for (int s = 128; s > 0; s >>= 1) {
        if (tid < s) sm[tid] += sm[tid + s];
        __syncthreads();
    }
    float inv = 1.f / sm[0];
    float* arow = attn + (size_t)b * Tt;
#pragma unroll
    for (int i = 0; i < 8; i++) arow[tid + i * 256] = e[i] * inv;
    for (int d = tid; d < Dd; d += 256) out[(size_t)b * 1024 + d] = col[(size_t)b * Dd + d];
}

// ---------------- kernel 4: weighted sums over COMPACTED t (R9 version) ------
__global__ void wsum_kernel(const float* __restrict__ attn, const float* __restrict__ X,
                            const int* __restrict__ cidx, const int* __restrict__ cnt,
                            float* __restrict__ part) {
    int dh = blockIdx.x;   // 0..1
    int tc = blockIdx.y;   // 0..3
    int b  = blockIdx.z;   // 0..127
    int tid = threadIdx.x; // 256
    int d = dh * 256 + tid;
    int count = cnt[b];
    int base = tc * 512;
    int lim = count - base; if (lim > 512) lim = 512; if (lim < 0) lim = 0;
    __shared__ float sa[512];
    __shared__ int  sidx[512];
    const int* crow = cidx + (size_t)b * Tt;
    for (int j = tid; j < 512; j += 256) {
        int r = base + j;
        bool v = r < count;
        int t = v ? crow[r] : 0;
        sidx[j] = t;
        sa[j] = v ? attn[(size_t)b * Tt + t] : 0.f;
    }
    __syncthreads();
    float acc = 0.f;
    const float* xb = X + (size_t)b * Tt * Dd + d;
#pragma unroll 4
    for (int j = 0; j < lim; j++) acc += sa[j] * xb[(size_t)sidx[j] * Dd];
    part[((size_t)b * 4 + tc) * Dd + d] = acc;
}

// ---------------- kernel 5: combine partials, write both outputs ----------------
__global__ void combine_kernel(const float* __restrict__ part, float* __restrict__ out) {
    int i = blockIdx.x * 256 + threadIdx.x;  // < 65536
    int b = i >> 9, d = i & 511;
    float s = 0.f;
#pragma unroll
    for (int tc = 0; tc < 4; tc++) s += part[((size_t)b * 4 + tc) * Dd + d];
    out[(size_t)b * 1024 + 512 + d] = s;                 // cat section, second half
    out[(size_t)Bb * 1024 + (size_t)b * 512 + d] = s;    // attention_output section
}

extern "C" void kernel_launch(void* const* d_in, const int* in_sizes, int n_in,
                              void* d_out, int out_size, void* d_ws, size_t ws_size,
                              hipStream_t stream) {
    const float* col  = (const float*)d_in[0];   // [128,512]
    const float* X    = (const float*)d_in[1];   // [128,2048,512]
    const int*   mask = (const int*)d_in[2];     // [128,2048]
    const float* W    = (const float*)d_in[3];   // [512,512]
    float* out = (float*)d_out;

    char* ws = (char*)d_ws;
    _Float16* W16   = (_Float16*)ws;                     // 0    .. 512K
    float*    colt  = (float*)(ws + (512 << 10));        // 512K .. 768K
    float*    scores= (float*)(ws + (768 << 10));        // 768K .. 1792K
    float*    attn  = scores;                            // softmax in-place
    float*    part  = (float*)(ws + (1792 << 10));       // 1792K.. 2816K
    int*      cidx  = (int*)(ws + (2816 << 10));         // 2816K.. 3840K
    int*      cnt   = (int*)(ws + (3840 << 10));         // 3840K.. +512B
    int*      tlist = (int*)(ws + (3841 << 10));         // 3841K.. +16KB
    int*      ntile = (int*)(ws + (3860 << 10));         // 3860K.. +4B

    hipMemsetAsync(ntile, 0, 4, stream);
    hipLaunchKernelGGL(prep_kernel, dim3(1408), dim3(256), 0, stream,
                       W, W16, mask, cidx, cnt, tlist, ntile, col, colt);
    hipLaunchKernelGGL(scores_kernel, dim3(NG), dim3(1024), 0, stream,
                       X, W16, colt, cidx, cnt, tlist, ntile, scores);
    hipLaunchKernelGGL(softmax_kernel, dim3(Bb), dim3(256), 0, stream, scores, mask, col, attn, out);
    hipLaunchKernelGGL(wsum_kernel, dim3(2, 4, Bb), dim3(256), 0, stream, attn, X, cidx, cnt, part);
    hipLaunchKernelGGL(combine_kernel, dim3(65536 / 256), dim3(256), 0, stream, part, out);
}